// Round 2
// baseline (455.013 us; speedup 1.0000x reference)
//
#include <hip/hip_runtime.h>

#define N_NODES   100000
#define N_EDGES   1600000
#define N_GRAPHS  256
#define D         32

// LDS accumulator transposed: acc[d][g] at d*N_GRAPHS + g -> bank = g % 32
// (random g ~= 2-way conflicts, free per m136).

__global__ __launch_bounds__(1024) void node_agg_kernel(
        const float* __restrict__ x,
        const int* __restrict__ batch,
        float* __restrict__ node_acc /* [G*D], g-major */) {
    __shared__ float lds[D * N_GRAPHS]; // 32 KB
    float4* lds4 = (float4*)lds;
    for (int i = threadIdx.x; i < D * N_GRAPHS / 4; i += blockDim.x)
        lds4[i] = make_float4(0.f, 0.f, 0.f, 0.f);
    __syncthreads();

    const float4* __restrict__ x4 = (const float4*)x;
    const int total = N_NODES * (D / 4);           // 800000 float4 units
    const int per_block = (total + gridDim.x - 1) / gridDim.x;
    const int start = blockIdx.x * per_block;
    const int end   = min(start + per_block, total);
    const int T = blockDim.x;

    int idx = start + (int)threadIdx.x;
    // 4-way batched unroll: all loads independent -> MLP in flight
    for (; idx + 3 * T < end; idx += 4 * T) {
        int   g[4];
        float4 v[4];
        #pragma unroll
        for (int k = 0; k < 4; ++k) g[k] = batch[(idx + k * T) >> 3];
        #pragma unroll
        for (int k = 0; k < 4; ++k) v[k] = x4[idx + k * T];
        #pragma unroll
        for (int k = 0; k < 4; ++k) {
            const int db = ((idx + k * T) & 7) * 4;
            unsafeAtomicAdd(&lds[(db + 0) * N_GRAPHS + g[k]], v[k].x);
            unsafeAtomicAdd(&lds[(db + 1) * N_GRAPHS + g[k]], v[k].y);
            unsafeAtomicAdd(&lds[(db + 2) * N_GRAPHS + g[k]], v[k].z);
            unsafeAtomicAdd(&lds[(db + 3) * N_GRAPHS + g[k]], v[k].w);
        }
    }
    for (; idx < end; idx += T) {
        const int g = batch[idx >> 3];
        float4 v = x4[idx];
        const int db = (idx & 7) * 4;
        unsafeAtomicAdd(&lds[(db + 0) * N_GRAPHS + g], v.x);
        unsafeAtomicAdd(&lds[(db + 1) * N_GRAPHS + g], v.y);
        unsafeAtomicAdd(&lds[(db + 2) * N_GRAPHS + g], v.z);
        unsafeAtomicAdd(&lds[(db + 3) * N_GRAPHS + g], v.w);
    }
    __syncthreads();

    // batch is sorted -> block's range spans few graphs, most cells stay 0
    for (int i = threadIdx.x; i < D * N_GRAPHS; i += blockDim.x) {
        const float v = lds[i];
        if (v != 0.f) {
            const int d = i >> 8;
            const int g = i & 255;
            unsafeAtomicAdd(&node_acc[g * D + d], v);
        }
    }
}

__global__ __launch_bounds__(1024) void edge_agg_kernel(
        const float* __restrict__ edge_attr,
        const int* __restrict__ edge_src,   // edge_index row 0
        const int* __restrict__ batch,
        float* __restrict__ edge_acc /* [G*D], g-major */) {
    __shared__ float lds[D * N_GRAPHS]; // 32 KB
    float4* lds4 = (float4*)lds;
    for (int i = threadIdx.x; i < D * N_GRAPHS / 4; i += blockDim.x)
        lds4[i] = make_float4(0.f, 0.f, 0.f, 0.f);
    __syncthreads();

    const float4* __restrict__ ea4 = (const float4*)edge_attr;
    const int total = N_EDGES * (D / 4);           // 12.8M float4 units
    const int per_block = (total + gridDim.x - 1) / gridDim.x;
    const int start = blockIdx.x * per_block;
    const int end   = min(start + per_block, total);
    const int T = blockDim.x;

    int idx = start + (int)threadIdx.x;
    // Two-stage batched unroll: 4 src loads, then 4 independent batch
    // gathers, then 4 independent float4 loads, then the LDS atomics.
    for (; idx + 3 * T < end; idx += 4 * T) {
        int    s[4];
        int    g[4];
        float4 v[4];
        #pragma unroll
        for (int k = 0; k < 4; ++k) s[k] = edge_src[(idx + k * T) >> 3];
        #pragma unroll
        for (int k = 0; k < 4; ++k) g[k] = batch[s[k]];
        #pragma unroll
        for (int k = 0; k < 4; ++k) v[k] = ea4[idx + k * T];
        #pragma unroll
        for (int k = 0; k < 4; ++k) {
            const int db = ((idx + k * T) & 7) * 4;
            unsafeAtomicAdd(&lds[(db + 0) * N_GRAPHS + g[k]], v[k].x);
            unsafeAtomicAdd(&lds[(db + 1) * N_GRAPHS + g[k]], v[k].y);
            unsafeAtomicAdd(&lds[(db + 2) * N_GRAPHS + g[k]], v[k].z);
            unsafeAtomicAdd(&lds[(db + 3) * N_GRAPHS + g[k]], v[k].w);
        }
    }
    for (; idx < end; idx += T) {
        const int g = batch[edge_src[idx >> 3]];
        float4 v = ea4[idx];
        const int db = (idx & 7) * 4;
        unsafeAtomicAdd(&lds[(db + 0) * N_GRAPHS + g], v.x);
        unsafeAtomicAdd(&lds[(db + 1) * N_GRAPHS + g], v.y);
        unsafeAtomicAdd(&lds[(db + 2) * N_GRAPHS + g], v.z);
        unsafeAtomicAdd(&lds[(db + 3) * N_GRAPHS + g], v.w);
    }
    __syncthreads();

    // random g -> essentially all cells nonzero; flush unconditionally
    for (int i = threadIdx.x; i < D * N_GRAPHS; i += blockDim.x) {
        const int d = i >> 8;
        const int g = i & 255;
        unsafeAtomicAdd(&edge_acc[g * D + d], lds[i]);
    }
}

// out[g][d] = relu(b[d] + sum_k concat(node_agg,edge_agg,u)[g][k] * W[k][d])
__global__ void mlp_kernel(const float* __restrict__ acc, // node_agg then edge_agg
                           const float* __restrict__ u,
                           const float* __restrict__ W,   // [3D][D]
                           const float* __restrict__ bias,
                           float* __restrict__ out) {
    __shared__ float Ws[3 * D * D]; // 12 KB
    for (int i = threadIdx.x; i < 3 * D * D; i += blockDim.x) Ws[i] = W[i];
    __syncthreads();

    const int t = blockIdx.x * blockDim.x + threadIdx.x; // 8192 threads
    const int g = t >> 5;
    const int d = t & 31;
    const float* __restrict__ nacc = acc;
    const float* __restrict__ eacc = acc + N_GRAPHS * D;

    float s = bias[d];
    #pragma unroll
    for (int k = 0; k < D; ++k) s += nacc[g * D + k] * Ws[k * D + d];
    #pragma unroll
    for (int k = 0; k < D; ++k) s += eacc[g * D + k] * Ws[(D + k) * D + d];
    #pragma unroll
    for (int k = 0; k < D; ++k) s += u[g * D + k] * Ws[(2 * D + k) * D + d];
    out[t] = fmaxf(s, 0.f);
}

extern "C" void kernel_launch(void* const* d_in, const int* in_sizes, int n_in,
                              void* d_out, int out_size, void* d_ws, size_t ws_size,
                              hipStream_t stream) {
    const float* x     = (const float*)d_in[0];
    const int*   ei    = (const int*)  d_in[1];  // [2, N_EDGES]; row 0 = src
    const float* ea    = (const float*)d_in[2];
    const float* u     = (const float*)d_in[3];
    const int*   batch = (const int*)  d_in[4];
    const float* W     = (const float*)d_in[5];
    const float* bias  = (const float*)d_in[6];
    float*       out   = (float*)d_out;

    float* acc = (float*)d_ws;                   // [2 * G * D] f32 = 64 KB
    hipMemsetAsync(d_ws, 0, 2 * N_GRAPHS * D * sizeof(float), stream);

    node_agg_kernel<<<256, 1024, 0, stream>>>(x, batch, acc);
    edge_agg_kernel<<<512, 1024, 0, stream>>>(ea, ei, batch, acc + N_GRAPHS * D);
    mlp_kernel<<<32, 256, 0, stream>>>(acc, u, W, bias, out);
}

// Round 3
// 358.009 us; speedup vs baseline: 1.2710x; 1.2710x over previous
//
#include <hip/hip_runtime.h>

#define N_NODES    100000
#define N_EDGES    1600000
#define N_GRAPHS   256
#define D          32
#define GD         (N_GRAPHS * D)   // 8192
#define LDS_STRIDE 257              // lds[d*257+g] -> bank = (d+g)%32

// ---------------- pass A: g8[e] = (u8) batch[src[e]] ----------------
__global__ __launch_bounds__(1024) void g8_kernel(const int* __restrict__ src,
                                                  const int* __restrict__ batch,
                                                  unsigned char* __restrict__ g8) {
    const int stride = gridDim.x * blockDim.x;
    int i = blockIdx.x * blockDim.x + threadIdx.x;
    for (; i + 3 * stride < N_EDGES; i += 4 * stride) {
        const int s0 = src[i];
        const int s1 = src[i + stride];
        const int s2 = src[i + 2 * stride];
        const int s3 = src[i + 3 * stride];
        const int b0 = batch[s0], b1 = batch[s1], b2 = batch[s2], b3 = batch[s3];
        g8[i]              = (unsigned char)b0;
        g8[i + stride]     = (unsigned char)b1;
        g8[i + 2 * stride] = (unsigned char)b2;
        g8[i + 3 * stride] = (unsigned char)b3;
    }
    for (; i < N_EDGES; i += stride) g8[i] = (unsigned char)batch[src[i]];
}

// ---------------- edge aggregation: LDS accumulate + partial write ----------------
__global__ __launch_bounds__(1024) void edge_agg_kernel(
        const float* __restrict__ edge_attr,
        const unsigned char* __restrict__ g8,
        float* __restrict__ partial /* [gridDim.x][GD], (g,d)-major */) {
    __shared__ float lds[D * LDS_STRIDE]; // 32.9 KB
    for (int i = threadIdx.x; i < D * LDS_STRIDE; i += blockDim.x) lds[i] = 0.f;
    __syncthreads();

    const float4* __restrict__ ea4 = (const float4*)edge_attr;
    const int total  = N_EDGES * (D / 4);    // 12.8M float4 units
    const int stride = gridDim.x * blockDim.x;
    int idx = blockIdx.x * blockDim.x + threadIdx.x;

    for (; idx + 3 * stride < total; idx += 4 * stride) {
        const int i0 = idx, i1 = idx + stride, i2 = idx + 2 * stride, i3 = idx + 3 * stride;
        const int G0 = g8[i0 >> 3];
        const int G1 = g8[i1 >> 3];
        const int G2 = g8[i2 >> 3];
        const int G3 = g8[i3 >> 3];
        const float4 v0 = ea4[i0];
        const float4 v1 = ea4[i1];
        const float4 v2 = ea4[i2];
        const float4 v3 = ea4[i3];
        const int d0 = (i0 & 7) * 4, d1 = (i1 & 7) * 4, d2 = (i2 & 7) * 4, d3 = (i3 & 7) * 4;
        unsafeAtomicAdd(&lds[(d0 + 0) * LDS_STRIDE + G0], v0.x);
        unsafeAtomicAdd(&lds[(d0 + 1) * LDS_STRIDE + G0], v0.y);
        unsafeAtomicAdd(&lds[(d0 + 2) * LDS_STRIDE + G0], v0.z);
        unsafeAtomicAdd(&lds[(d0 + 3) * LDS_STRIDE + G0], v0.w);
        unsafeAtomicAdd(&lds[(d1 + 0) * LDS_STRIDE + G1], v1.x);
        unsafeAtomicAdd(&lds[(d1 + 1) * LDS_STRIDE + G1], v1.y);
        unsafeAtomicAdd(&lds[(d1 + 2) * LDS_STRIDE + G1], v1.z);
        unsafeAtomicAdd(&lds[(d1 + 3) * LDS_STRIDE + G1], v1.w);
        unsafeAtomicAdd(&lds[(d2 + 0) * LDS_STRIDE + G2], v2.x);
        unsafeAtomicAdd(&lds[(d2 + 1) * LDS_STRIDE + G2], v2.y);
        unsafeAtomicAdd(&lds[(d2 + 2) * LDS_STRIDE + G2], v2.z);
        unsafeAtomicAdd(&lds[(d2 + 3) * LDS_STRIDE + G2], v2.w);
        unsafeAtomicAdd(&lds[(d3 + 0) * LDS_STRIDE + G3], v3.x);
        unsafeAtomicAdd(&lds[(d3 + 1) * LDS_STRIDE + G3], v3.y);
        unsafeAtomicAdd(&lds[(d3 + 2) * LDS_STRIDE + G3], v3.z);
        unsafeAtomicAdd(&lds[(d3 + 3) * LDS_STRIDE + G3], v3.w);
    }
    for (; idx < total; idx += stride) {
        const int G = g8[idx >> 3];
        const float4 v = ea4[idx];
        const int db = (idx & 7) * 4;
        unsafeAtomicAdd(&lds[(db + 0) * LDS_STRIDE + G], v.x);
        unsafeAtomicAdd(&lds[(db + 1) * LDS_STRIDE + G], v.y);
        unsafeAtomicAdd(&lds[(db + 2) * LDS_STRIDE + G], v.z);
        unsafeAtomicAdd(&lds[(db + 3) * LDS_STRIDE + G], v.w);
    }
    __syncthreads();

    // plain coalesced store of this block's partial (no atomics)
    float* __restrict__ my = partial + (size_t)blockIdx.x * GD;
    for (int i = threadIdx.x; i < GD; i += blockDim.x) {
        const int g = i >> 5;   // (g,d)-major
        const int d = i & 31;
        my[i] = lds[d * LDS_STRIDE + g];   // conflict-free: banks (d+g)%32 distinct
    }
}

// ---------------- node aggregation (batch sorted -> g load coalesced) ----------------
__global__ __launch_bounds__(1024) void node_agg_kernel(
        const float* __restrict__ x,
        const int* __restrict__ batch,
        float* __restrict__ partial /* [gridDim.x][GD] */) {
    __shared__ float lds[D * LDS_STRIDE];
    for (int i = threadIdx.x; i < D * LDS_STRIDE; i += blockDim.x) lds[i] = 0.f;
    __syncthreads();

    const float4* __restrict__ x4 = (const float4*)x;
    const int total  = N_NODES * (D / 4);   // 800000
    const int stride = gridDim.x * blockDim.x;
    int idx = blockIdx.x * blockDim.x + threadIdx.x;

    for (; idx + 3 * stride < total; idx += 4 * stride) {
        const int i0 = idx, i1 = idx + stride, i2 = idx + 2 * stride, i3 = idx + 3 * stride;
        const int G0 = batch[i0 >> 3];
        const int G1 = batch[i1 >> 3];
        const int G2 = batch[i2 >> 3];
        const int G3 = batch[i3 >> 3];
        const float4 v0 = x4[i0];
        const float4 v1 = x4[i1];
        const float4 v2 = x4[i2];
        const float4 v3 = x4[i3];
        const int d0 = (i0 & 7) * 4, d1 = (i1 & 7) * 4, d2 = (i2 & 7) * 4, d3 = (i3 & 7) * 4;
        unsafeAtomicAdd(&lds[(d0 + 0) * LDS_STRIDE + G0], v0.x);
        unsafeAtomicAdd(&lds[(d0 + 1) * LDS_STRIDE + G0], v0.y);
        unsafeAtomicAdd(&lds[(d0 + 2) * LDS_STRIDE + G0], v0.z);
        unsafeAtomicAdd(&lds[(d0 + 3) * LDS_STRIDE + G0], v0.w);
        unsafeAtomicAdd(&lds[(d1 + 0) * LDS_STRIDE + G1], v1.x);
        unsafeAtomicAdd(&lds[(d1 + 1) * LDS_STRIDE + G1], v1.y);
        unsafeAtomicAdd(&lds[(d1 + 2) * LDS_STRIDE + G1], v1.z);
        unsafeAtomicAdd(&lds[(d1 + 3) * LDS_STRIDE + G1], v1.w);
        unsafeAtomicAdd(&lds[(d2 + 0) * LDS_STRIDE + G2], v2.x);
        unsafeAtomicAdd(&lds[(d2 + 1) * LDS_STRIDE + G2], v2.y);
        unsafeAtomicAdd(&lds[(d2 + 2) * LDS_STRIDE + G2], v2.z);
        unsafeAtomicAdd(&lds[(d2 + 3) * LDS_STRIDE + G2], v2.w);
        unsafeAtomicAdd(&lds[(d3 + 0) * LDS_STRIDE + G3], v3.x);
        unsafeAtomicAdd(&lds[(d3 + 1) * LDS_STRIDE + G3], v3.y);
        unsafeAtomicAdd(&lds[(d3 + 2) * LDS_STRIDE + G3], v3.z);
        unsafeAtomicAdd(&lds[(d3 + 3) * LDS_STRIDE + G3], v3.w);
    }
    for (; idx < total; idx += stride) {
        const int G = batch[idx >> 3];
        const float4 v = x4[idx];
        const int db = (idx & 7) * 4;
        unsafeAtomicAdd(&lds[(db + 0) * LDS_STRIDE + G], v.x);
        unsafeAtomicAdd(&lds[(db + 1) * LDS_STRIDE + G], v.y);
        unsafeAtomicAdd(&lds[(db + 2) * LDS_STRIDE + G], v.z);
        unsafeAtomicAdd(&lds[(db + 3) * LDS_STRIDE + G], v.w);
    }
    __syncthreads();

    float* __restrict__ my = partial + (size_t)blockIdx.x * GD;
    for (int i = threadIdx.x; i < GD; i += blockDim.x) {
        const int g = i >> 5;
        const int d = i & 31;
        my[i] = lds[d * LDS_STRIDE + g];
    }
}

// ---------------- tree reduce of partials -> acc[node GD | edge GD] ----------------
__global__ void reduce_kernel(const float* __restrict__ npart, int nn,
                              const float* __restrict__ epart, int ne,
                              float* __restrict__ acc) {
    const int t = blockIdx.x * blockDim.x + threadIdx.x; // 2*GD threads
    if (t < GD) {
        float s = 0.f;
        #pragma unroll 4
        for (int p = 0; p < nn; ++p) s += npart[(size_t)p * GD + t];
        acc[t] = s;
    } else {
        const int t2 = t - GD;
        float s = 0.f;
        #pragma unroll 4
        for (int p = 0; p < ne; ++p) s += epart[(size_t)p * GD + t2];
        acc[GD + t2] = s;
    }
}

// ---------------- MLP: out = relu([nacc|eacc|u] @ W + b) ----------------
__global__ void mlp_kernel(const float* __restrict__ acc, // node then edge
                           const float* __restrict__ u,
                           const float* __restrict__ W,   // [3D][D]
                           const float* __restrict__ bias,
                           float* __restrict__ out) {
    __shared__ float Ws[3 * D * D]; // 12 KB
    for (int i = threadIdx.x; i < 3 * D * D; i += blockDim.x) Ws[i] = W[i];
    __syncthreads();

    const int t = blockIdx.x * blockDim.x + threadIdx.x; // 8192 threads
    const int g = t >> 5;
    const int d = t & 31;
    const float* __restrict__ nacc = acc;
    const float* __restrict__ eacc = acc + GD;

    float s = bias[d];
    #pragma unroll
    for (int k = 0; k < D; ++k) s += nacc[g * D + k] * Ws[k * D + d];
    #pragma unroll
    for (int k = 0; k < D; ++k) s += eacc[g * D + k] * Ws[(D + k) * D + d];
    #pragma unroll
    for (int k = 0; k < D; ++k) s += u[g * D + k] * Ws[(2 * D + k) * D + d];
    out[t] = fmaxf(s, 0.f);
}

extern "C" void kernel_launch(void* const* d_in, const int* in_sizes, int n_in,
                              void* d_out, int out_size, void* d_ws, size_t ws_size,
                              hipStream_t stream) {
    const float* x     = (const float*)d_in[0];
    const int*   ei    = (const int*)  d_in[1];  // [2, N_EDGES]; row 0 = src
    const float* ea    = (const float*)d_in[2];
    const float* u     = (const float*)d_in[3];
    const int*   batch = (const int*)  d_in[4];
    const float* W     = (const float*)d_in[5];
    const float* bias  = (const float*)d_in[6];
    float*       out   = (float*)d_out;

    // ws layout: [g8 bytes][edge partials][node partials][acc 2*GD]
    const size_t g8_bytes = (size_t)((N_EDGES + 255) & ~255);
    int ne = 512, nn = 128;
    {
        size_t need = g8_bytes + (size_t)(ne + nn + 2) * GD * sizeof(float);
        if (need > ws_size) { ne = 128; nn = 64; }
        need = g8_bytes + (size_t)(ne + nn + 2) * GD * sizeof(float);
        if (need > ws_size) { ne = 32; nn = 16; }
        need = g8_bytes + (size_t)(ne + nn + 2) * GD * sizeof(float);
        if (need > ws_size) { ne = 8; nn = 4; }
    }
    unsigned char* g8    = (unsigned char*)d_ws;
    float*         epart = (float*)((char*)d_ws + g8_bytes);
    float*         npart = epart + (size_t)ne * GD;
    float*         acc   = npart + (size_t)nn * GD;

    g8_kernel<<<256, 1024, 0, stream>>>(ei, batch, g8);
    edge_agg_kernel<<<ne, 1024, 0, stream>>>(ea, g8, epart);
    node_agg_kernel<<<nn, 1024, 0, stream>>>(x, batch, npart);
    reduce_kernel<<<(2 * GD) / 256, 256, 0, stream>>>(npart, nn, epart, ne, acc);
    mlp_kernel<<<GD / 256, 256, 0, stream>>>(acc, u, W, bias, out);
}